// Round 5
// baseline (481.964 us; speedup 1.0000x reference)
//
#include <hip/hip_runtime.h>
#include <hip/hip_bf16.h>
#include <cstdint>
#include <cstddef>

typedef short s16x8 __attribute__((ext_vector_type(8)));
typedef float f32x4 __attribute__((ext_vector_type(4)));

#define DEV static __device__ __forceinline__

DEV unsigned short f2bf(float x){
  union { float f; unsigned int u; } v; v.f = x;
  unsigned int u = v.u;
  return (unsigned short)((u + 0x7FFFu + ((u >> 16) & 1u)) >> 16);
}
DEV float bf2f(unsigned short b){
  union { unsigned int u; float f; } v; v.u = ((unsigned int)b) << 16;
  return v.f;
}

// async global->LDS 16B (wave-uniform LDS base + lane*16; global addr per-lane)
DEV void gld16(unsigned short* lds, const unsigned short* g){
  __builtin_amdgcn_global_load_lds(
      (const __attribute__((address_space(1))) void*)g,
      (__attribute__((address_space(3))) void*)lds, 16, 0, 0);
}

// ---------------- cast & gather ----------------
__global__ __launch_bounds__(256) void cast_x(const float* __restrict__ X,
                                              unsigned short* __restrict__ out){
  int i = (blockIdx.x*256 + threadIdx.x)*4;
  float4 v = *(const float4*)(X + i);
  ushort4 r;
  r.x = f2bf(v.x); r.y = f2bf(v.y); r.z = f2bf(v.z); r.w = f2bf(v.w);
  *(ushort4*)(out + i) = r;
}

__global__ __launch_bounds__(256) void xg_gather(const float* __restrict__ X,
                                                 unsigned short* __restrict__ Xg){
  int idx = blockIdx.x*256 + threadIdx.x;           // < 131072
  int row = idx >> 10, c = idx & 1023;
  int b = row >> 6, g = row & 63;
  Xg[idx] = f2bf(X[(size_t)(b*4096 + g)*1024 + c]);
}

__global__ __launch_bounds__(256) void bias_cat_k(
    const float* bq, const float* bk, const float* bv,
    const float* bkg, const float* bvg, const float* bqg,
    float* __restrict__ bc, float* __restrict__ bqg_o){
  int i = blockIdx.x*256 + threadIdx.x;             // < 6144
  if (i < 5120){
    int slot = i >> 10, c = i & 1023;
    const float* s = (slot==0)?bq:(slot==1)?bk:(slot==2)?bv:(slot==3)?bkg:bvg;
    bc[i] = s[c];
  } else {
    bqg_o[i-5120] = bqg[i-5120];
  }
}

// ---------------- weight transpose: W[k][n] fp32 -> Wt[n][k] bf16 ----------------
struct WSrc { const float* p[6]; };

__global__ __launch_bounds__(256) void wt_transpose(WSrc srcs,
    unsigned short* __restrict__ Wtcat, unsigned short* __restrict__ Wtqg){
  __shared__ float t[64*66];
  int bi = blockIdx.x;
  int widx = bi >> 8;                 // 0..5 input order q,k,v,qg,kg,vg
  int tile = bi & 255;
  int tn = tile & 15, tk = tile >> 4;
  int k0 = tk*64, n0 = tn*64;
  const float* W = srcs.p[widx];
  int tid = threadIdx.x;
  for (int it=0; it<8; ++it){
    int flat = it*256 + tid;          // 2048 float2
    int r = flat >> 5, ch = flat & 31;
    *(float2*)&t[r*66 + ch*2] = *(const float2*)(W + (size_t)(k0+r)*1024 + n0 + ch*2);
  }
  __syncthreads();
  unsigned short* dst = (widx==3) ? Wtqg
                      : Wtcat + (size_t)((widx<3)?widx:widx-1)*1048576;
  for (int it=0; it<16; ++it){
    int flat = it*256 + tid;          // 4096 elems
    int i = flat >> 6, j = flat & 63;
    dst[(size_t)(n0+i)*1024 + k0 + j] = f2bf(t[j*66 + i]);
  }
}

// ---------------- bf16 MFMA GEMM (m97 structure): C = A·Bt^T ----------------
__global__ __launch_bounds__(256) void gemm_bt(
    const unsigned short* __restrict__ A, const unsigned short* __restrict__ Bt,
    const float* __restrict__ bias, unsigned short* __restrict__ C,
    int Astr, int Bstr, int Cstr, int scale_cols)
{
  __shared__ unsigned short lA[128*64];   // linear: global_load_lds needs it
  __shared__ unsigned short lB[128*64];
  int tid = threadIdx.x, lane = tid & 63, wv = tid >> 6;
  int wm = wv >> 1, wn = wv & 1;
  int lane15 = lane & 15, kh = (lane >> 4) << 3;
  int m0 = blockIdx.y*128, n0 = blockIdx.x*128;
  f32x4 acc[4][4];
  for (int i=0;i<4;i++) for (int j=0;j<4;j++) acc[i][j] = (f32x4){0.f,0.f,0.f,0.f};
  for (int k0 = 0; k0 < 1024; k0 += 64){
#pragma unroll
    for (int it = 0; it < 4; ++it){
      int chunk = it*256 + tid;       // 1024 chunks of 16B per 128x64 tile
      int r = chunk >> 3, ch = (chunk & 7) << 3;
      gld16(&lA[chunk*8], A  + (size_t)(m0+r)*Astr + k0 + ch);
      gld16(&lB[chunk*8], Bt + (size_t)(n0+r)*Bstr + k0 + ch);
    }
    __syncthreads();
#pragma unroll
    for (int ks = 0; ks < 2; ++ks){
      s16x8 af[4], bfr[4];
#pragma unroll
      for (int i=0;i<4;i++)
        af[i] = *(const s16x8*)&lA[(wm*64 + i*16 + lane15)*64 + ks*32 + kh];
#pragma unroll
      for (int j=0;j<4;j++)
        bfr[j] = *(const s16x8*)&lB[(wn*64 + j*16 + lane15)*64 + ks*32 + kh];
#pragma unroll
      for (int i=0;i<4;i++)
#pragma unroll
        for (int j=0;j<4;j++)
          acc[i][j] = __builtin_amdgcn_mfma_f32_16x16x32_bf16(af[i], bfr[j], acc[i][j], 0,0,0);
    }
    __syncthreads();
  }
  for (int i=0;i<4;i++){
    int mb = m0 + wm*64 + i*16 + ((lane>>4)<<2);
    for (int j=0;j<4;j++){
      int n = n0 + wn*64 + j*16 + lane15;
      float bb = bias[n];
      float sc = (n < scale_cols) ? 0.125f : 1.0f;
#pragma unroll
      for (int r=0;r<4;r++)
        C[(size_t)(mb+r)*Cstr + n] = f2bf((acc[i][j][r] + bb)*sc);
    }
  }
}

// ---------------- proj col-slice -> t[b][h][d][s] (s-contiguous) ----------------
__global__ __launch_bounds__(256) void vt_transpose(
    const unsigned short* __restrict__ proj, unsigned short* __restrict__ dst,
    int coloff){
  __shared__ unsigned short t[64*72];
  int bi = blockIdx.x;
  int sc = bi & 63, h = (bi>>6) & 15, b = bi >> 10;
  int s0 = sc*64;
  int tid = threadIdx.x;
  for (int it=0; it<2; ++it){
    int flat = it*256 + tid;          // 512 16B-chunks
    int r = flat >> 3, ch = flat & 7;
    *(int4*)&t[r*72 + ch*8] =
      *(const int4*)(proj + (size_t)(b*4096+s0+r)*5120 + coloff + h*64 + ch*8);
  }
  __syncthreads();
  for (int it=0; it<2; ++it){
    int flat = it*256 + tid;
    int d = flat & 63, ch = flat >> 6; // 0..7
    unsigned short tmp[8];
#pragma unroll
    for (int j=0;j<8;j++) tmp[j] = t[(ch*8+j)*72 + d];
    *(int4*)(dst + ((size_t)(b*16+h)*64 + d)*4096 + s0 + ch*8) = *(int4*)tmp;
  }
}

// ---------------- fused sliding-window + global-prefix attention ----------------
// Scores stored PRE-SKEWED: row r, score col c -> sS col c + (c>=64 ? r : 0).
// After softmax, row r's e-values are rewritten in place as bf16 (aliased view),
// so the PV MFMA A-fragment is a direct b128 read. Normalization (rs*mz) is
// deferred to the PV epilogue via srs[16].
#define SSTR 612
__global__ __launch_bounds__(256) void sliding_attn(
    const unsigned short* __restrict__ proj,   // [8192][5120]: q|k|v|kg|vg
    const unsigned short* __restrict__ vt,     // [2][16][64][4096]
    const float* __restrict__ amask,           // [2][4096]
    const unsigned char* __restrict__ maskb,   // is_index_masked (bytes; all 0)
    float* __restrict__ probs,                 // [2][4096][16][577]
    float* __restrict__ attn)                  // [2][4096][1024]
{
  __shared__ float sS[16*SSTR];                // 39168 B (scores f32 -> e bf16)
  __shared__ float srs[16];                    // per-row rs*mz for PV epilogue
  int bi = blockIdx.x;
  int ti = bi & 255, h = (bi>>8) & 15, b = bi >> 12;
  int t = ti*16;
  int chk = t >> 8;
  int qu = (chk < 15) ? chk*256 : 3584;
  int ql = (chk >= 1) ? chk*256 : 256;
  int tid = threadIdx.x, lane = tid & 63, wv = tid >> 6;
  int lane15 = lane & 15, kh = (lane >> 4) << 3;
  int rbase = (lane>>4)<<2;

  // A fragments: q rows t.. (global cols), k rows t.. (up), k rows t-1.. (low)
  s16x8 aq0, aq1, ak0a, ak0b, ak1a, ak1b;
  {
    int qrow = t + lane15;
    const unsigned short* qp = proj + (size_t)(b*4096+qrow)*5120 + h*64 + kh;
    aq0 = *(const s16x8*)qp;  aq1 = *(const s16x8*)(qp + 32);
    const unsigned short* kp0 = proj + (size_t)(b*4096+qrow)*5120 + 1024 + h*64 + kh;
    ak0a = *(const s16x8*)kp0; ak0b = *(const s16x8*)(kp0 + 32);
    int krow = t - 1 + lane15; if (krow < 0) krow = 0;
    const unsigned short* kp1 = proj + (size_t)(b*4096+krow)*5120 + 1024 + h*64 + kh;
    ak1a = *(const s16x8*)kp1; ak1b = *(const s16x8*)(kp1 + 32);
  }

  // QK: tiles interleaved by wave (ct = wv, wv+4, ...), 1-deep B prefetch.
  // First tile (ct=wv<4) is the global-key tile; the rest are window tiles.
  {
    int colg = wv*16 + lane15;                 // 0..63
    const unsigned short* gp_ = proj + (size_t)(b*4096+colg)*5120 + 1024 + h*64 + kh;
    s16x8 b0 = *(const s16x8*)gp_, b1 = *(const s16x8*)(gp_+32);
    int ct = wv + 4;
    const unsigned short* np;
    s16x8 n0, n1;
    {
      int col = ct*16 + lane15;
      int brow = (ct < 20) ? (ql + 1 + col - 64) : (qu + col - 320);
      if (brow > 4095) brow = 4095;
      np = proj + (size_t)(b*4096+brow)*5120 + h*64 + kh;
      n0 = *(const s16x8*)np; n1 = *(const s16x8*)(np+32);
    }
    f32x4 acc = (f32x4){0.f,0.f,0.f,0.f};
    acc = __builtin_amdgcn_mfma_f32_16x16x32_bf16(aq0, b0, acc, 0,0,0);
    acc = __builtin_amdgcn_mfma_f32_16x16x32_bf16(aq1, b1, acc, 0,0,0);
#pragma unroll
    for (int r=0;r<4;r++) sS[(rbase+r)*SSTR + colg] = acc[r];
    while (ct < 37){
      b0 = n0; b1 = n1;
      int ctc = ct;
      ct += 4;
      if (ct < 37){
        int col = ct*16 + lane15;
        int brow = (ct < 20) ? (ql + 1 + col - 64) : (qu + col - 320);
        if (brow > 4095) brow = 4095;
        np = proj + (size_t)(b*4096+brow)*5120 + h*64 + kh;
        n0 = *(const s16x8*)np; n1 = *(const s16x8*)(np+32);
      }
      s16x8 A0 = (ctc < 20) ? ak1a : ak0a;
      s16x8 A1 = (ctc < 20) ? ak1b : ak0b;
      acc = (f32x4){0.f,0.f,0.f,0.f};
      acc = __builtin_amdgcn_mfma_f32_16x16x32_bf16(A0, b0, acc, 0,0,0);
      acc = __builtin_amdgcn_mfma_f32_16x16x32_bf16(A1, b1, acc, 0,0,0);
      int col = ctc*16 + lane15;
#pragma unroll
      for (int r=0;r<4;r++){
        int row = rbase + r;
        sS[row*SSTR + col + row] = acc[r];   // window cols always skewed
      }
    }
  }
  __syncthreads();

  // softmax: wave wv owns rows wv*4..wv*4+3; register-cached (1 read, 1 exp)
  for (int rr=0; rr<4; ++rr){
    int r = wv*4 + rr, s = t + r;
    int ii = s & 255;
    float low_add = (s >= 1) ? amask[b*4096 + s - 1] : 0.f;
    float up_add  = amask[b*4096 + s];
    float* srow = &sS[r*SSTR];
    unsigned short* sprow = (unsigned short*)srow;   // bf16 alias of this row
    float ereg[10];
    float m = -1e30f;
#pragma unroll
    for (int i=0;i<10;i++){
      int c = lane + i*64;
      float v = -1e30f;
      if (c < 577){
        v = srow[c + ((c>=64) ? r : 0)];
        if (c >= 320){                      // up col j = c-320
          int j = c - 320;
          bool valid = !((chk==15) & (j >= 256 - ii));
          v = valid ? v + up_add : -1e30f;
        } else if (c >= 64){                // low col j = c-64
          int j = c - 64;
          bool valid = !((chk==0) & (j < 256 - ii));
          v = valid ? ((j==255) ? 0.f : v + low_add) : -1e30f;
        }
      }
      ereg[i] = v;
      m = fmaxf(m, v);
    }
#pragma unroll
    for (int o=32;o;o>>=1) m = fmaxf(m, __shfl_xor(m, o));
    float sum = 0.f;
#pragma unroll
    for (int i=0;i<10;i++){
      int c = lane + i*64;
      if (c < 577){
        float e = __expf(ereg[i] - m);
        ereg[i] = e;
        sum += e;
        sprow[c + ((c>=64) ? r : 0)] = f2bf(e);   // unnormalized e, bf16
      }
    }
#pragma unroll
    for (int o=32;o;o>>=1) sum += __shfl_xor(sum, o);
    float rs = 1.f / sum;
    float mz = maskb[b*4096 + s] ? 0.f : 1.f;
    float pz = (s < 64) ? 0.f : mz;
    float* prow = probs + ((size_t)(b*4096+s)*16 + h)*577;
#pragma unroll
    for (int i=0;i<10;i++){
      int c = lane + i*64;
      if (c < 577) prow[c] = ereg[i] * rs * pz;
    }
    // zero bf16 gaps: cols [64..63+r] and [577+r..607] (31 cols total)
    if (lane < 31){
      int zc = (lane < r) ? 64 + lane : 577 + lane;
      sprow[zc] = 0;
    }
    if (lane == 0) srs[r] = rs * mz;
  }
  __syncthreads();

  // PV: out[16][64]; wave wv owns d-subtile; K-dim = 608 (19 chunks of 32)
  // bf16 e-row r lives at (unsigned short*)(sS + r*SSTR), cols 0..607
  int dcol = wv*16 + lane15;
  const unsigned short* vtb = vt + ((size_t)(b*16+h)*64 + dcol)*4096;
  const unsigned short* prow16 = (const unsigned short*)(sS + (size_t)lane15*SSTR);
  f32x4 oacc = (f32x4){0.f,0.f,0.f,0.f};
#pragma unroll
  for (int kc = 0; kc < 19; ++kc){
    int kk = kc*32 + kh;
    s16x8 ap = *(const s16x8*)(prow16 + kk);
    int key = (kk < 64) ? kk : (t - 320 + kk);
    key = key < 0 ? 0 : (key > 4088 ? 4088 : key);  // e=0 there anyway
    s16x8 bv = *(const s16x8*)(vtb + key);
    oacc = __builtin_amdgcn_mfma_f32_16x16x32_bf16(ap, bv, oacc, 0,0,0);
  }
#pragma unroll
  for (int r=0;r<4;r++)
    attn[(size_t)(b*4096 + t + rbase + r)*1024 + h*64 + dcol] = oacc[r] * srs[rbase + r];
}

// ---------------- global attention: gs = qg·kg^T (raw scores into gp) ----------------
__global__ __launch_bounds__(256) void gs_a(
    const unsigned short* __restrict__ qg,     // [128][1024]
    const unsigned short* __restrict__ proj,   // kg at col 3072
    const unsigned char* __restrict__ maskb,
    float* __restrict__ gp)                    // [2][16][64][4096] raw
{
  __shared__ float sQ[64*64];
  int bi = blockIdx.x;
  int sc = bi & 15, h = (bi>>4) & 15, b = bi >> 8;
  int tid = threadIdx.x;
  for (int it=0; it<16; ++it){
    int flat = it*256 + tid;
    int g = flat >> 6, d = flat & 63;
    sQ[flat] = bf2f(qg[(size_t)(b*64+g)*1024 + h*64 + d]);
  }
  __syncthreads();
  int s = sc*256 + tid;
  float kreg[64];
  {
    const s16x8* kp = (const s16x8*)(proj + (size_t)(b*4096+s)*5120 + 3072 + h*64);
#pragma unroll
    for (int i=0;i<8;i++){
      s16x8 kv = kp[i];
#pragma unroll
      for (int j=0;j<8;j++) kreg[i*8+j] = bf2f((unsigned short)kv[j]);
    }
  }
  bool msk = maskb[b*4096 + s] != 0;
  float* out = gp + (size_t)(b*16+h)*64*4096 + s;
  for (int g=0; g<64; ++g){
    const float4* qrow = (const float4*)&sQ[g*64];
    float acc = 0.f;
#pragma unroll
    for (int i=0;i<16;i++){
      float4 qv = qrow[i];
      acc += qv.x*kreg[4*i] + qv.y*kreg[4*i+1] + qv.z*kreg[4*i+2] + qv.w*kreg[4*i+3];
    }
    out[(size_t)g*4096] = msk ? -10000.f : acc;
  }
}

// normalize gp rows in place (softmax over s), also emit bf16 copy
__global__ __launch_bounds__(256) void gs_norm(float* __restrict__ gp,
                                               unsigned short* __restrict__ gpb){
  __shared__ float red[8];
  int bi = blockIdx.x;                          // b*1024 + h*64 + g
  float* row = gp + (size_t)bi*4096;
  int tid = threadIdx.x, lane = tid & 63, wv = tid >> 6;
  float m = -1e30f;
  for (int i=tid; i<4096; i+=256) m = fmaxf(m, row[i]);
#pragma unroll
  for (int o=32;o;o>>=1) m = fmaxf(m, __shfl_xor(m, o));
  if (!lane) red[wv] = m;
  __syncthreads();
  m = fmaxf(fmaxf(red[0],red[1]), fmaxf(red[2],red[3]));
  float s = 0.f;
  for (int i=tid; i<4096; i+=256) s += __expf(row[i] - m);
#pragma unroll
  for (int o=32;o;o>>=1) s += __shfl_xor(s, o);
  if (!lane) red[4+wv] = s;
  __syncthreads();
  s = red[4]+red[5]+red[6]+red[7];
  float rs = 1.f / s;
  for (int i=tid; i<4096; i+=256){
    float p = __expf(row[i] - m) * rs;
    row[i] = p;
    gpb[(size_t)bi*4096 + i] = f2bf(p);
  }
}

// go partial GEMM: gop[bh][kc][64][64] = gp_bf[bh][g][kslice]·vgt[bh][d][kslice]^T
__global__ __launch_bounds__(256) void go_mfma(
    const unsigned short* __restrict__ gpb,    // [32][64][4096] bf16
    const unsigned short* __restrict__ vgt,    // [32][64][4096] bf16
    float* __restrict__ gop)                   // [32][8][64][64] f32
{
  int bi = blockIdx.x;
  int kc = bi & 7, bh = bi >> 3;
  int tid = threadIdx.x, lane = tid & 63, wv = tid >> 6;
  int lane15 = lane & 15, kh = (lane >> 4) << 3;
  const unsigned short* arow = gpb + ((size_t)bh*64 + wv*16 + lane15)*4096 + kh;
  const unsigned short* bbase = vgt + (size_t)bh*64*4096 + kh;
  f32x4 acc[4];
#pragma unroll
  for (int j=0;j<4;j++) acc[j] = (f32x4){0.f,0.f,0.f,0.f};
  for (int ks = 0; ks < 16; ++ks){
    int k = kc*512 + ks*32;
    s16x8 a = *(const s16x8*)(arow + k);
#pragma unroll
    for (int j=0;j<4;j++){
      s16x8 bv = *(const s16x8*)(bbase + (size_t)(j*16 + lane15)*4096 + k);
      acc[j] = __builtin_amdgcn_mfma_f32_16x16x32_bf16(a, bv, acc[j], 0,0,0);
    }
  }
  int rq = (lane >> 4) << 2;
  float* o = gop + ((size_t)bh*8 + kc)*4096;
#pragma unroll
  for (int j=0;j<4;j++)
#pragma unroll
    for (int r=0;r<4;r++)
      o[(wv*16 + rq + r)*64 + j*16 + lane15] = acc[j][r];
}

__global__ __launch_bounds__(256) void reduce_go2(
    const float* __restrict__ gop, float* __restrict__ attn){
  int flat = blockIdx.x*256 + threadIdx.x;    // < 131072
  int gd = flat & 4095, bh = flat >> 12;
  int b = bh >> 4, h = bh & 15;
  int g = gd >> 6, d = gd & 63;
  const float* p = gop + (size_t)bh*8*4096 + gd;
  float sum = 0.f;
#pragma unroll
  for (int c=0; c<8; ++c) sum += p[c*4096];
  attn[(size_t)(b*4096 + g)*1024 + h*64 + d] = sum;
}

// ---------------- launcher ----------------
extern "C" void kernel_launch(void* const* d_in, const int* in_sizes, int n_in,
                              void* d_out, int out_size, void* d_ws, size_t ws_size,
                              hipStream_t stream)
{
  const float* X     = (const float*)d_in[0];
  const float* amask = (const float*)d_in[1];
  const float* Wq  = (const float*)d_in[2];  const float* bq  = (const float*)d_in[3];
  const float* Wk  = (const float*)d_in[4];  const float* bk  = (const float*)d_in[5];
  const float* Wv  = (const float*)d_in[6];  const float* bv  = (const float*)d_in[7];
  const float* Wqg = (const float*)d_in[8];  const float* bqg = (const float*)d_in[9];
  const float* Wkg = (const float*)d_in[10]; const float* bkg = (const float*)d_in[11];
  const float* Wvg = (const float*)d_in[12]; const float* bvg = (const float*)d_in[13];
  const unsigned char* imask = (const unsigned char*)d_in[14];
  (void)in_sizes; (void)n_in; (void)out_size;

  // ws layout (bytes)
  const size_t XBF  = 0;               // 16,777,216 (Xbf; later gp_bf — exact fit)
  const size_t XG   = 16777216;        // 262,144
  const size_t WT   = 17039360;        // 10,485,760 (Wt cat; later gop 4 MB)
  const size_t WTQG = 27525120;        // 2,097,152
  const size_t BC   = 29622272;        // 20,480
  const size_t BQG  = 29642752;        // 4,096
  const size_t PROJ = 29646848;        // 83,886,080 ([8192][5120] bf16)
  const size_t QGO  = 113532928;       // 262,144
  const size_t VT   = 113795072;       // 16,777,216 (v^T; later vg^T — reuse)
  const size_t NEED = 130572288;
  if (ws_size < NEED) return;          // fail loudly (output stays poisoned)

  char* ws = (char*)d_ws;
  unsigned short* Xbf   = (unsigned short*)(ws + XBF);
  unsigned short* Xg    = (unsigned short*)(ws + XG);
  unsigned short* Wtcat = (unsigned short*)(ws + WT);
  unsigned short* Wtqg  = (unsigned short*)(ws + WTQG);
  float*          bc    = (float*)(ws + BC);
  float*          bqgo  = (float*)(ws + BQG);
  unsigned short* proj  = (unsigned short*)(ws + PROJ);
  unsigned short* qgo   = (unsigned short*)(ws + QGO);
  unsigned short* vt    = (unsigned short*)(ws + VT);
  unsigned short* gpb   = (unsigned short*)(ws + XBF);   // reuse Xbf (16.7 MB exact)
  float*          gop   = (float*)(ws + WT);             // reuse Wt region (4 MB)

  float* attn  = (float*)d_out;
  float* probs = (float*)d_out + 8388608;
  float* gp    = (float*)d_out + 84017152;

  cast_x<<<8192, 256, 0, stream>>>(X, Xbf);
  xg_gather<<<512, 256, 0, stream>>>(X, Xg);
  bias_cat_k<<<24, 256, 0, stream>>>(bq, bk, bv, bkg, bvg, bqg, bc, bqgo);
  WSrc srcs; srcs.p[0]=Wq; srcs.p[1]=Wk; srcs.p[2]=Wv; srcs.p[3]=Wqg; srcs.p[4]=Wkg; srcs.p[5]=Wvg;
  wt_transpose<<<1536, 256, 0, stream>>>(srcs, Wtcat, Wtqg);
  gemm_bt<<<dim3(40,64), 256, 0, stream>>>(Xbf, Wtcat, bc, proj, 1024, 1024, 5120, 1024);
  gemm_bt<<<dim3(8,1),  256, 0, stream>>>(Xg, Wtqg, bqgo, qgo, 1024, 1024, 1024, 1024);
  vt_transpose<<<2048, 256, 0, stream>>>(proj, vt, 2048);        // v^T
  sliding_attn<<<8192, 256, 0, stream>>>(proj, vt, amask, imask, probs, attn);
  vt_transpose<<<2048, 256, 0, stream>>>(proj, vt, 4096);        // vg^T (reuse buffer)
  gs_a<<<512, 256, 0, stream>>>(qgo, proj, imask, gp);
  gs_norm<<<2048, 256, 0, stream>>>(gp, gpb);
  go_mfma<<<256, 256, 0, stream>>>(gpb, vt, gop);
  reduce_go2<<<512, 256, 0, stream>>>(gop, attn);
}

// Round 6
// 443.581 us; speedup vs baseline: 1.0865x; 1.0865x over previous
//
#include <hip/hip_runtime.h>
#include <hip/hip_bf16.h>
#include <cstdint>
#include <cstddef>

typedef short s16x8 __attribute__((ext_vector_type(8)));
typedef float f32x4 __attribute__((ext_vector_type(4)));

#define DEV static __device__ __forceinline__

DEV unsigned short f2bf(float x){
  union { float f; unsigned int u; } v; v.f = x;
  unsigned int u = v.u;
  return (unsigned short)((u + 0x7FFFu + ((u >> 16) & 1u)) >> 16);
}
DEV float bf2f(unsigned short b){
  union { unsigned int u; float f; } v; v.u = ((unsigned int)b) << 16;
  return v.f;
}

// async global->LDS 16B (wave-uniform LDS base + lane*16; global addr per-lane)
DEV void gld16(unsigned short* lds, const unsigned short* g){
  __builtin_amdgcn_global_load_lds(
      (const __attribute__((address_space(1))) void*)g,
      (__attribute__((address_space(3))) void*)lds, 16, 0, 0);
}

// ---------------- cast & gather ----------------
__global__ __launch_bounds__(256) void cast_x(const float* __restrict__ X,
                                              unsigned short* __restrict__ out){
  int i = (blockIdx.x*256 + threadIdx.x)*4;
  float4 v = *(const float4*)(X + i);
  ushort4 r;
  r.x = f2bf(v.x); r.y = f2bf(v.y); r.z = f2bf(v.z); r.w = f2bf(v.w);
  *(ushort4*)(out + i) = r;
}

__global__ __launch_bounds__(256) void xg_gather(const float* __restrict__ X,
                                                 unsigned short* __restrict__ Xg){
  int idx = blockIdx.x*256 + threadIdx.x;           // < 131072
  int row = idx >> 10, c = idx & 1023;
  int b = row >> 6, g = row & 63;
  Xg[idx] = f2bf(X[(size_t)(b*4096 + g)*1024 + c]);
}

__global__ __launch_bounds__(256) void bias_cat_k(
    const float* bq, const float* bk, const float* bv,
    const float* bkg, const float* bvg, const float* bqg,
    float* __restrict__ bc, float* __restrict__ bqg_o){
  int i = blockIdx.x*256 + threadIdx.x;             // < 6144
  if (i < 5120){
    int slot = i >> 10, c = i & 1023;
    const float* s = (slot==0)?bq:(slot==1)?bk:(slot==2)?bv:(slot==3)?bkg:bvg;
    bc[i] = s[c];
  } else {
    bqg_o[i-5120] = bqg[i-5120];
  }
}

// ---------------- weight transpose: W[k][n] fp32 -> Wt[n][k] bf16 ----------------
struct WSrc { const float* p[6]; };

__global__ __launch_bounds__(256) void wt_transpose(WSrc srcs,
    unsigned short* __restrict__ Wtcat, unsigned short* __restrict__ Wtqg){
  __shared__ float t[64*66];
  int bi = blockIdx.x;
  int widx = bi >> 8;                 // 0..5 input order q,k,v,qg,kg,vg
  int tile = bi & 255;
  int tn = tile & 15, tk = tile >> 4;
  int k0 = tk*64, n0 = tn*64;
  const float* W = srcs.p[widx];
  int tid = threadIdx.x;
  for (int it=0; it<8; ++it){
    int flat = it*256 + tid;          // 2048 float2
    int r = flat >> 5, ch = flat & 31;
    *(float2*)&t[r*66 + ch*2] = *(const float2*)(W + (size_t)(k0+r)*1024 + n0 + ch*2);
  }
  __syncthreads();
  unsigned short* dst = (widx==3) ? Wtqg
                      : Wtcat + (size_t)((widx<3)?widx:widx-1)*1048576;
  for (int it=0; it<16; ++it){
    int flat = it*256 + tid;          // 4096 elems
    int i = flat >> 6, j = flat & 63;
    dst[(size_t)(n0+i)*1024 + k0 + j] = f2bf(t[j*66 + i]);
  }
}

// ---------------- bf16 MFMA GEMM (m97 + T2 swizzle): C = A·Bt^T ----------------
// LDS linear (global_load_lds), source chunk pre-swizzled ch^=(r&7); reads XOR back.
__global__ __launch_bounds__(256) void gemm_bt(
    const unsigned short* __restrict__ A, const unsigned short* __restrict__ Bt,
    const float* __restrict__ bias, unsigned short* __restrict__ C,
    int Astr, int Bstr, int Cstr, int scale_cols)
{
  __shared__ unsigned short lA[128*64];
  __shared__ unsigned short lB[128*64];
  int tid = threadIdx.x, lane = tid & 63, wv = tid >> 6;
  int wm = wv >> 1, wn = wv & 1;
  int lane15 = lane & 15, kh = (lane >> 4) << 3;
  int m0 = blockIdx.y*128, n0 = blockIdx.x*128;
  f32x4 acc[4][4];
  for (int i=0;i<4;i++) for (int j=0;j<4;j++) acc[i][j] = (f32x4){0.f,0.f,0.f,0.f};
  for (int k0 = 0; k0 < 1024; k0 += 64){
#pragma unroll
    for (int it = 0; it < 4; ++it){
      int chunk = it*256 + tid;       // 1024 chunks of 16B per 128x64 tile
      int r = chunk >> 3, ch = chunk & 7;
      int co = ((ch ^ (r & 7)) << 3);
      gld16(&lA[chunk*8], A  + (size_t)(m0+r)*Astr + k0 + co);
      gld16(&lB[chunk*8], Bt + (size_t)(n0+r)*Bstr + k0 + co);
    }
    __syncthreads();
#pragma unroll
    for (int ks = 0; ks < 2; ++ks){
      s16x8 af[4], bfr[4];
#pragma unroll
      for (int i=0;i<4;i++){
        int row = wm*64 + i*16 + lane15;
        af[i] = *(const s16x8*)&lA[(row<<6) + ((ks*32 + kh) ^ ((row&7)<<3))];
      }
#pragma unroll
      for (int j=0;j<4;j++){
        int row = wn*64 + j*16 + lane15;
        bfr[j] = *(const s16x8*)&lB[(row<<6) + ((ks*32 + kh) ^ ((row&7)<<3))];
      }
#pragma unroll
      for (int i=0;i<4;i++)
#pragma unroll
        for (int j=0;j<4;j++)
          acc[i][j] = __builtin_amdgcn_mfma_f32_16x16x32_bf16(af[i], bfr[j], acc[i][j], 0,0,0);
    }
    __syncthreads();
  }
  for (int i=0;i<4;i++){
    int mb = m0 + wm*64 + i*16 + ((lane>>4)<<2);
    for (int j=0;j<4;j++){
      int n = n0 + wn*64 + j*16 + lane15;
      float bb = bias[n];
      float sc = (n < scale_cols) ? 0.125f : 1.0f;
#pragma unroll
      for (int r=0;r<4;r++)
        C[(size_t)(mb+r)*Cstr + n] = f2bf((acc[i][j][r] + bb)*sc);
    }
  }
}

// ---------------- proj col-slice -> t[b][h][d][s] (s-contiguous) ----------------
__global__ __launch_bounds__(256) void vt_transpose(
    const unsigned short* __restrict__ proj, unsigned short* __restrict__ dst,
    int coloff){
  __shared__ unsigned short t[64*72];
  int bi = blockIdx.x;
  int sc = bi & 63, h = (bi>>6) & 15, b = bi >> 10;
  int s0 = sc*64;
  int tid = threadIdx.x;
  for (int it=0; it<2; ++it){
    int flat = it*256 + tid;          // 512 16B-chunks
    int r = flat >> 3, ch = flat & 7;
    *(int4*)&t[r*72 + ch*8] =
      *(const int4*)(proj + (size_t)(b*4096+s0+r)*5120 + coloff + h*64 + ch*8);
  }
  __syncthreads();
  for (int it=0; it<2; ++it){
    int flat = it*256 + tid;
    int d = flat & 63, ch = flat >> 6; // 0..7
    unsigned short tmp[8];
#pragma unroll
    for (int j=0;j<8;j++) tmp[j] = t[(ch*8+j)*72 + d];
    *(int4*)(dst + ((size_t)(b*16+h)*64 + d)*4096 + s0 + ch*8) = *(int4*)tmp;
  }
}

// ---------------- fused sliding-window + global-prefix attention ----------------
// Scores stored PRE-SKEWED: row r, score col c -> sS col c + (c>=64 ? r : 0).
// Softmax processes the wave's 4 rows INTERLEAVED (4x ILP on loads/reduces/exp).
// e-values rewritten in place as bf16; PV A-fragment is a direct b128 read.
// Normalization (rs*mz) deferred to PV epilogue via srs[16].
#define SSTR 612
__global__ __launch_bounds__(256) void sliding_attn(
    const unsigned short* __restrict__ proj,   // [8192][5120]: q|k|v|kg|vg
    const unsigned short* __restrict__ vt,     // [2][16][64][4096]
    const float* __restrict__ amask,           // [2][4096]
    const unsigned char* __restrict__ maskb,   // is_index_masked (bytes; all 0)
    float* __restrict__ probs,                 // [2][4096][16][577]
    float* __restrict__ attn)                  // [2][4096][1024]
{
  __shared__ float sS[16*SSTR];                // 39168 B (scores f32 -> e bf16)
  __shared__ float srs[16];                    // per-row rs*mz for PV epilogue
  int bi = blockIdx.x;
  int ti = bi & 255, h = (bi>>8) & 15, b = bi >> 12;
  int t = ti*16;
  int chk = t >> 8;
  int qu = (chk < 15) ? chk*256 : 3584;
  int ql = (chk >= 1) ? chk*256 : 256;
  int tid = threadIdx.x, lane = tid & 63, wv = tid >> 6;
  int lane15 = lane & 15, kh = (lane >> 4) << 3;
  int rbase = (lane>>4)<<2;

  // A fragments: q rows t.. (global cols), k rows t.. (up), k rows t-1.. (low)
  s16x8 aq0, aq1, ak0a, ak0b, ak1a, ak1b;
  {
    int qrow = t + lane15;
    const unsigned short* qp = proj + (size_t)(b*4096+qrow)*5120 + h*64 + kh;
    aq0 = *(const s16x8*)qp;  aq1 = *(const s16x8*)(qp + 32);
    const unsigned short* kp0 = proj + (size_t)(b*4096+qrow)*5120 + 1024 + h*64 + kh;
    ak0a = *(const s16x8*)kp0; ak0b = *(const s16x8*)(kp0 + 32);
    int krow = t - 1 + lane15; if (krow < 0) krow = 0;
    const unsigned short* kp1 = proj + (size_t)(b*4096+krow)*5120 + 1024 + h*64 + kh;
    ak1a = *(const s16x8*)kp1; ak1b = *(const s16x8*)(kp1 + 32);
  }

  // QK: tiles interleaved by wave (ct = wv, wv+4, ...), 1-deep B prefetch.
  {
    int colg = wv*16 + lane15;                 // 0..63
    const unsigned short* gp_ = proj + (size_t)(b*4096+colg)*5120 + 1024 + h*64 + kh;
    s16x8 b0 = *(const s16x8*)gp_, b1 = *(const s16x8*)(gp_+32);
    int ct = wv + 4;
    const unsigned short* np;
    s16x8 n0, n1;
    {
      int col = ct*16 + lane15;
      int brow = (ct < 20) ? (ql + 1 + col - 64) : (qu + col - 320);
      if (brow > 4095) brow = 4095;
      np = proj + (size_t)(b*4096+brow)*5120 + h*64 + kh;
      n0 = *(const s16x8*)np; n1 = *(const s16x8*)(np+32);
    }
    f32x4 acc = (f32x4){0.f,0.f,0.f,0.f};
    acc = __builtin_amdgcn_mfma_f32_16x16x32_bf16(aq0, b0, acc, 0,0,0);
    acc = __builtin_amdgcn_mfma_f32_16x16x32_bf16(aq1, b1, acc, 0,0,0);
#pragma unroll
    for (int r=0;r<4;r++) sS[(rbase+r)*SSTR + colg] = acc[r];
    while (ct < 37){
      b0 = n0; b1 = n1;
      int ctc = ct;
      ct += 4;
      if (ct < 37){
        int col = ct*16 + lane15;
        int brow = (ct < 20) ? (ql + 1 + col - 64) : (qu + col - 320);
        if (brow > 4095) brow = 4095;
        np = proj + (size_t)(b*4096+brow)*5120 + h*64 + kh;
        n0 = *(const s16x8*)np; n1 = *(const s16x8*)(np+32);
      }
      s16x8 A0 = (ctc < 20) ? ak1a : ak0a;
      s16x8 A1 = (ctc < 20) ? ak1b : ak0b;
      acc = (f32x4){0.f,0.f,0.f,0.f};
      acc = __builtin_amdgcn_mfma_f32_16x16x32_bf16(A0, b0, acc, 0,0,0);
      acc = __builtin_amdgcn_mfma_f32_16x16x32_bf16(A1, b1, acc, 0,0,0);
      int col = ctc*16 + lane15;
#pragma unroll
      for (int r=0;r<4;r++){
        int row = rbase + r;
        sS[row*SSTR + col + row] = acc[r];   // window cols always skewed
      }
    }
  }
  __syncthreads();

  // softmax: wave wv owns rows wv*4..wv*4+3, all 4 interleaved
  {
    int r0 = wv*4;
    float low_add[4], up_add[4];
#pragma unroll
    for (int rr=0;rr<4;rr++){
      int s = t + r0 + rr;
      low_add[rr] = (s >= 1) ? amask[b*4096 + s - 1] : 0.f;
      up_add[rr]  = amask[b*4096 + s];
    }
    float ereg[4][10];
    float m4[4] = {-1e30f,-1e30f,-1e30f,-1e30f};
#pragma unroll
    for (int i=0;i<10;i++){
      int c = lane + i*64;
      bool inr = (c < 577);
      bool isup = (c >= 320), islow = (c >= 64) & !isup;
      int jup = c - 320, jlow = c - 64;
#pragma unroll
      for (int rr=0;rr<4;rr++){
        int r = r0 + rr;
        float v = -1e30f;
        if (inr){
          v = sS[r*SSTR + c + ((c>=64) ? r : 0)];
          int ii = (t + r) & 255;
          if (isup){
            bool valid = !((chk==15) & (jup >= 256 - ii));
            v = valid ? v + up_add[rr] : -1e30f;
          } else if (islow){
            bool valid = !((chk==0) & (jlow < 256 - ii));
            v = valid ? ((jlow==255) ? 0.f : v + low_add[rr]) : -1e30f;
          }
        }
        ereg[rr][i] = v;
        m4[rr] = fmaxf(m4[rr], v);
      }
    }
#pragma unroll
    for (int o=32;o;o>>=1){
#pragma unroll
      for (int rr=0;rr<4;rr++) m4[rr] = fmaxf(m4[rr], __shfl_xor(m4[rr], o));
    }
    float sum4[4] = {0.f,0.f,0.f,0.f};
#pragma unroll
    for (int i=0;i<10;i++){
      int c = lane + i*64;
      if (c < 577){
#pragma unroll
        for (int rr=0;rr<4;rr++){
          int r = r0 + rr;
          float e = __expf(ereg[rr][i] - m4[rr]);
          ereg[rr][i] = e;
          sum4[rr] += e;
          ((unsigned short*)&sS[r*SSTR])[c + ((c>=64) ? r : 0)] = f2bf(e);
        }
      }
    }
#pragma unroll
    for (int o=32;o;o>>=1){
#pragma unroll
      for (int rr=0;rr<4;rr++) sum4[rr] += __shfl_xor(sum4[rr], o);
    }
#pragma unroll
    for (int rr=0;rr<4;rr++){
      int r = r0 + rr, s = t + r;
      float rs = 1.f / sum4[rr];
      float mz = maskb[b*4096 + s] ? 0.f : 1.f;
      float pz = (s < 64) ? 0.f : mz;
      float* prow = probs + ((size_t)(b*4096+s)*16 + h)*577;
#pragma unroll
      for (int i=0;i<10;i++){
        int c = lane + i*64;
        if (c < 577) prow[c] = ereg[rr][i] * rs * pz;
      }
      // zero bf16 gaps: cols [64..63+r] and [577+r..607] (31 cols total)
      if (lane < 31){
        int zc = (lane < r) ? 64 + lane : 577 + lane;
        ((unsigned short*)&sS[r*SSTR])[zc] = 0;
      }
      if (lane == 0) srs[r] = rs * mz;
    }
  }
  __syncthreads();

  // PV: out[16][64]; wave wv owns d-subtile; K-dim = 608 (19 chunks of 32)
  int dcol = wv*16 + lane15;
  const unsigned short* vtb = vt + ((size_t)(b*16+h)*64 + dcol)*4096;
  const unsigned short* prow16 = (const unsigned short*)(sS + (size_t)lane15*SSTR);
  f32x4 oacc = (f32x4){0.f,0.f,0.f,0.f};
#pragma unroll
  for (int kc = 0; kc < 19; ++kc){
    int kk = kc*32 + kh;
    s16x8 ap = *(const s16x8*)(prow16 + kk);
    int key = (kk < 64) ? kk : (t - 320 + kk);
    key = key < 0 ? 0 : (key > 4088 ? 4088 : key);  // e=0 there anyway
    s16x8 bv = *(const s16x8*)(vtb + key);
    oacc = __builtin_amdgcn_mfma_f32_16x16x32_bf16(ap, bv, oacc, 0,0,0);
  }
#pragma unroll
  for (int r=0;r<4;r++)
    attn[(size_t)(b*4096 + t + rbase + r)*1024 + h*64 + dcol] = oacc[r] * srs[rbase + r];
}

// ---------------- global attention: gs = qg·kg^T (raw scores into gp) ----------------
__global__ __launch_bounds__(256) void gs_a(
    const unsigned short* __restrict__ qg,     // [128][1024]
    const unsigned short* __restrict__ proj,   // kg at col 3072
    const unsigned char* __restrict__ maskb,
    float* __restrict__ gp)                    // [2][16][64][4096] raw
{
  __shared__ float sQ[64*64];
  int bi = blockIdx.x;
  int sc = bi & 15, h = (bi>>4) & 15, b = bi >> 8;
  int tid = threadIdx.x;
  for (int it=0; it<16; ++it){
    int flat = it*256 + tid;
    int g = flat >> 6, d = flat & 63;
    sQ[flat] = bf2f(qg[(size_t)(b*64+g)*1024 + h*64 + d]);
  }
  __syncthreads();
  int s = sc*256 + tid;
  float kreg[64];
  {
    const s16x8* kp = (const s16x8*)(proj + (size_t)(b*4096+s)*5120 + 3072 + h*64);
#pragma unroll
    for (int i=0;i<8;i++){
      s16x8 kv = kp[i];
#pragma unroll
      for (int j=0;j<8;j++) kreg[i*8+j] = bf2f((unsigned short)kv[j]);
    }
  }
  bool msk = maskb[b*4096 + s] != 0;
  float* out = gp + (size_t)(b*16+h)*64*4096 + s;
  for (int g=0; g<64; ++g){
    const float4* qrow = (const float4*)&sQ[g*64];
    float acc = 0.f;
#pragma unroll
    for (int i=0;i<16;i++){
      float4 qv = qrow[i];
      acc += qv.x*kreg[4*i] + qv.y*kreg[4*i+1] + qv.z*kreg[4*i+2] + qv.w*kreg[4*i+3];
    }
    out[(size_t)g*4096] = msk ? -10000.f : acc;
  }
}

// normalize gp rows in place (softmax over s), single pass, also emit bf16 copy
__global__ __launch_bounds__(256) void gs_norm(float* __restrict__ gp,
                                               unsigned short* __restrict__ gpb){
  __shared__ float red[8];
  int bi = blockIdx.x;                          // b*1024 + h*64 + g
  float* row = gp + (size_t)bi*4096;
  int tid = threadIdx.x, lane = tid & 63, wv = tid >> 6;
  float v[16];
  float m = -1e30f;
#pragma unroll
  for (int i=0;i<16;i++){
    v[i] = row[tid + i*256];
    m = fmaxf(m, v[i]);
  }
#pragma unroll
  for (int o=32;o;o>>=1) m = fmaxf(m, __shfl_xor(m, o));
  if (!lane) red[wv] = m;
  __syncthreads();
  m = fmaxf(fmaxf(red[0],red[1]), fmaxf(red[2],red[3]));
  float s = 0.f;
#pragma unroll
  for (int i=0;i<16;i++){
    float e = __expf(v[i] - m);
    v[i] = e;
    s += e;
  }
#pragma unroll
  for (int o=32;o;o>>=1) s += __shfl_xor(s, o);
  if (!lane) red[4+wv] = s;
  __syncthreads();
  s = red[4]+red[5]+red[6]+red[7];
  float rs = 1.f / s;
#pragma unroll
  for (int i=0;i<16;i++){
    float p = v[i] * rs;
    row[tid + i*256] = p;
    gpb[(size_t)bi*4096 + tid + i*256] = f2bf(p);
  }
}

// go partial GEMM: gop[bh][kc][64][64] = gp_bf[bh][g][kslice]·vgt[bh][d][kslice]^T
__global__ __launch_bounds__(256) void go_mfma(
    const unsigned short* __restrict__ gpb,    // [32][64][4096] bf16
    const unsigned short* __restrict__ vgt,    // [32][64][4096] bf16
    float* __restrict__ gop)                   // [32][8][64][64] f32
{
  int bi = blockIdx.x;
  int kc = bi & 7, bh = bi >> 3;
  int tid = threadIdx.x, lane = tid & 63, wv = tid >> 6;
  int lane15 = lane & 15, kh = (lane >> 4) << 3;
  const unsigned short* arow = gpb + ((size_t)bh*64 + wv*16 + lane15)*4096 + kh;
  const unsigned short* bbase = vgt + (size_t)bh*64*4096 + kh;
  f32x4 acc[4];
#pragma unroll
  for (int j=0;j<4;j++) acc[j] = (f32x4){0.f,0.f,0.f,0.f};
  for (int ks = 0; ks < 16; ++ks){
    int k = kc*512 + ks*32;
    s16x8 a = *(const s16x8*)(arow + k);
#pragma unroll
    for (int j=0;j<4;j++){
      s16x8 bv = *(const s16x8*)(bbase + (size_t)(j*16 + lane15)*4096 + k);
      acc[j] = __builtin_amdgcn_mfma_f32_16x16x32_bf16(a, bv, acc[j], 0,0,0);
    }
  }
  int rq = (lane >> 4) << 2;
  float* o = gop + ((size_t)bh*8 + kc)*4096;
#pragma unroll
  for (int j=0;j<4;j++)
#pragma unroll
    for (int r=0;r<4;r++)
      o[(wv*16 + rq + r)*64 + j*16 + lane15] = acc[j][r];
}

__global__ __launch_bounds__(256) void reduce_go2(
    const float* __restrict__ gop, float* __restrict__ attn){
  int flat = blockIdx.x*256 + threadIdx.x;    // < 131072
  int gd = flat & 4095, bh = flat >> 12;
  int b = bh >> 4, h = bh & 15;
  int g = gd >> 6, d = gd & 63;
  const float* p = gop + (size_t)bh*8*4096 + gd;
  float sum = 0.f;
#pragma unroll
  for (int c=0; c<8; ++c) sum += p[c*4096];
  attn[(size_t)(b*4096 + g)*1024 + h*64 + d] = sum;
}

// ---------------- launcher ----------------
extern "C" void kernel_launch(void* const* d_in, const int* in_sizes, int n_in,
                              void* d_out, int out_size, void* d_ws, size_t ws_size,
                              hipStream_t stream)
{
  const float* X     = (const float*)d_in[0];
  const float* amask = (const float*)d_in[1];
  const float* Wq  = (const float*)d_in[2];  const float* bq  = (const float*)d_in[3];
  const float* Wk  = (const float*)d_in[4];  const float* bk  = (const float*)d_in[5];
  const float* Wv  = (const float*)d_in[6];  const float* bv  = (const float*)d_in[7];
  const float* Wqg = (const float*)d_in[8];  const float* bqg = (const float*)d_in[9];
  const float* Wkg = (const float*)d_in[10]; const float* bkg = (const float*)d_in[11];
  const float* Wvg = (const float*)d_in[12]; const float* bvg = (const float*)d_in[13];
  const unsigned char* imask = (const unsigned char*)d_in[14];
  (void)in_sizes; (void)n_in; (void)out_size;

  // ws layout (bytes)
  const size_t XBF  = 0;               // 16,777,216 (Xbf; later gp_bf — exact fit)
  const size_t XG   = 16777216;        // 262,144
  const size_t WT   = 17039360;        // 10,485,760 (Wt cat; later gop 4 MB)
  const size_t WTQG = 27525120;        // 2,097,152
  const size_t BC   = 29622272;        // 20,480
  const size_t BQG  = 29642752;        // 4,096
  const size_t PROJ = 29646848;        // 83,886,080 ([8192][5120] bf16)
  const size_t QGO  = 113532928;       // 262,144
  const size_t VT   = 113795072;       // 16,777,216 (v^T; later vg^T — reuse)
  const size_t NEED = 130572288;
  if (ws_size < NEED) return;          // fail loudly (output stays poisoned)

  char* ws = (char*)d_ws;
  unsigned short* Xbf   = (unsigned short*)(ws + XBF);
  unsigned short* Xg    = (unsigned short*)(ws + XG);
  unsigned short* Wtcat = (unsigned short*)(ws + WT);
  unsigned short* Wtqg  = (unsigned short*)(ws + WTQG);
  float*          bc    = (float*)(ws + BC);
  float*          bqgo  = (float*)(ws + BQG);
  unsigned short* proj  = (unsigned short*)(ws + PROJ);
  unsigned short* qgo   = (unsigned short*)(ws + QGO);
  unsigned short* vt    = (unsigned short*)(ws + VT);
  unsigned short* gpb   = (unsigned short*)(ws + XBF);   // reuse Xbf (16.7 MB exact)
  float*          gop   = (float*)(ws + WT);             // reuse Wt region (4 MB)

  float* attn  = (float*)d_out;
  float* probs = (float*)d_out + 8388608;
  float* gp    = (float*)d_out + 84017152;

  cast_x<<<8192, 256, 0, stream>>>(X, Xbf);
  xg_gather<<<512, 256, 0, stream>>>(X, Xg);
  bias_cat_k<<<24, 256, 0, stream>>>(bq, bk, bv, bkg, bvg, bqg, bc, bqgo);
  WSrc srcs; srcs.p[0]=Wq; srcs.p[1]=Wk; srcs.p[2]=Wv; srcs.p[3]=Wqg; srcs.p[4]=Wkg; srcs.p[5]=Wvg;
  wt_transpose<<<1536, 256, 0, stream>>>(srcs, Wtcat, Wtqg);
  gemm_bt<<<dim3(40,64), 256, 0, stream>>>(Xbf, Wtcat, bc, proj, 1024, 1024, 5120, 1024);
  gemm_bt<<<dim3(8,1),  256, 0, stream>>>(Xg, Wtqg, bqgo, qgo, 1024, 1024, 1024, 1024);
  vt_transpose<<<2048, 256, 0, stream>>>(proj, vt, 2048);        // v^T
  sliding_attn<<<8192, 256, 0, stream>>>(proj, vt, amask, imask, probs, attn);
  vt_transpose<<<2048, 256, 0, stream>>>(proj, vt, 4096);        // vg^T (reuse buffer)
  gs_a<<<512, 256, 0, stream>>>(qgo, proj, imask, gp);
  gs_norm<<<2048, 256, 0, stream>>>(gp, gpb);
  go_mfma<<<256, 256, 0, stream>>>(gpb, vt, gop);
  reduce_go2<<<512, 256, 0, stream>>>(gop, attn);
}

// Round 7
// 420.058 us; speedup vs baseline: 1.1474x; 1.0560x over previous
//
#include <hip/hip_runtime.h>
#include <hip/hip_bf16.h>
#include <cstdint>
#include <cstddef>

typedef short s16x8 __attribute__((ext_vector_type(8)));
typedef float f32x4 __attribute__((ext_vector_type(4)));

#define DEV static __device__ __forceinline__

DEV unsigned short f2bf(float x){
  union { float f; unsigned int u; } v; v.f = x;
  unsigned int u = v.u;
  return (unsigned short)((u + 0x7FFFu + ((u >> 16) & 1u)) >> 16);
}
DEV float bf2f(unsigned short b){
  union { unsigned int u; float f; } v; v.u = ((unsigned int)b) << 16;
  return v.f;
}

// async global->LDS 16B (wave-uniform LDS base + lane*16; global addr per-lane)
DEV void gld16(unsigned short* lds, const unsigned short* g){
  __builtin_amdgcn_global_load_lds(
      (const __attribute__((address_space(1))) void*)g,
      (__attribute__((address_space(3))) void*)lds, 16, 0, 0);
}

// ---------------- cast & gather ----------------
__global__ __launch_bounds__(256) void cast_x(const float* __restrict__ X,
                                              unsigned short* __restrict__ out){
  int i = (blockIdx.x*256 + threadIdx.x)*4;
  float4 v = *(const float4*)(X + i);
  ushort4 r;
  r.x = f2bf(v.x); r.y = f2bf(v.y); r.z = f2bf(v.z); r.w = f2bf(v.w);
  *(ushort4*)(out + i) = r;
}

__global__ __launch_bounds__(256) void xg_gather(const float* __restrict__ X,
                                                 unsigned short* __restrict__ Xg){
  int idx = blockIdx.x*256 + threadIdx.x;           // < 131072
  int row = idx >> 10, c = idx & 1023;
  int b = row >> 6, g = row & 63;
  Xg[idx] = f2bf(X[(size_t)(b*4096 + g)*1024 + c]);
}

__global__ __launch_bounds__(256) void bias_cat_k(
    const float* bq, const float* bk, const float* bv,
    const float* bkg, const float* bvg, const float* bqg,
    float* __restrict__ bc, float* __restrict__ bqg_o){
  int i = blockIdx.x*256 + threadIdx.x;             // < 6144
  if (i < 5120){
    int slot = i >> 10, c = i & 1023;
    const float* s = (slot==0)?bq:(slot==1)?bk:(slot==2)?bv:(slot==3)?bkg:bvg;
    bc[i] = s[c];
  } else {
    bqg_o[i-5120] = bqg[i-5120];
  }
}

// ---------------- weight transpose: W[k][n] fp32 -> Wt[n][k] bf16 ----------------
struct WSrc { const float* p[6]; };

__global__ __launch_bounds__(256) void wt_transpose(WSrc srcs,
    unsigned short* __restrict__ Wtcat, unsigned short* __restrict__ Wtqg){
  __shared__ float t[64*66];
  int bi = blockIdx.x;
  int widx = bi >> 8;                 // 0..5 input order q,k,v,qg,kg,vg
  int tile = bi & 255;
  int tn = tile & 15, tk = tile >> 4;
  int k0 = tk*64, n0 = tn*64;
  const float* W = srcs.p[widx];
  int tid = threadIdx.x;
  for (int it=0; it<8; ++it){
    int flat = it*256 + tid;          // 2048 float2
    int r = flat >> 5, ch = flat & 31;
    *(float2*)&t[r*66 + ch*2] = *(const float2*)(W + (size_t)(k0+r)*1024 + n0 + ch*2);
  }
  __syncthreads();
  unsigned short* dst = (widx==3) ? Wtqg
                      : Wtcat + (size_t)((widx<3)?widx:widx-1)*1048576;
  for (int it=0; it<16; ++it){
    int flat = it*256 + tid;          // 4096 elems
    int i = flat >> 6, j = flat & 63;
    dst[(size_t)(n0+i)*1024 + k0 + j] = f2bf(t[j*66 + i]);
  }
}

// ---------------- bf16 MFMA GEMM (m97 + T2 swizzle): C = A·Bt^T ----------------
__global__ __launch_bounds__(256) void gemm_bt(
    const unsigned short* __restrict__ A, const unsigned short* __restrict__ Bt,
    const float* __restrict__ bias, unsigned short* __restrict__ C,
    int Astr, int Bstr, int Cstr, int scale_cols)
{
  __shared__ unsigned short lA[128*64];
  __shared__ unsigned short lB[128*64];
  int tid = threadIdx.x, lane = tid & 63, wv = tid >> 6;
  int wm = wv >> 1, wn = wv & 1;
  int lane15 = lane & 15, kh = (lane >> 4) << 3;
  int m0 = blockIdx.y*128, n0 = blockIdx.x*128;
  f32x4 acc[4][4];
  for (int i=0;i<4;i++) for (int j=0;j<4;j++) acc[i][j] = (f32x4){0.f,0.f,0.f,0.f};
  for (int k0 = 0; k0 < 1024; k0 += 64){
#pragma unroll
    for (int it = 0; it < 4; ++it){
      int chunk = it*256 + tid;       // 1024 chunks of 16B per 128x64 tile
      int r = chunk >> 3, ch = chunk & 7;
      int co = ((ch ^ (r & 7)) << 3);
      gld16(&lA[chunk*8], A  + (size_t)(m0+r)*Astr + k0 + co);
      gld16(&lB[chunk*8], Bt + (size_t)(n0+r)*Bstr + k0 + co);
    }
    __syncthreads();
#pragma unroll
    for (int ks = 0; ks < 2; ++ks){
      s16x8 af[4], bfr[4];
#pragma unroll
      for (int i=0;i<4;i++){
        int row = wm*64 + i*16 + lane15;
        af[i] = *(const s16x8*)&lA[(row<<6) + ((ks*32 + kh) ^ ((row&7)<<3))];
      }
#pragma unroll
      for (int j=0;j<4;j++){
        int row = wn*64 + j*16 + lane15;
        bfr[j] = *(const s16x8*)&lB[(row<<6) + ((ks*32 + kh) ^ ((row&7)<<3))];
      }
#pragma unroll
      for (int i=0;i<4;i++)
#pragma unroll
        for (int j=0;j<4;j++)
          acc[i][j] = __builtin_amdgcn_mfma_f32_16x16x32_bf16(af[i], bfr[j], acc[i][j], 0,0,0);
    }
    __syncthreads();
  }
  for (int i=0;i<4;i++){
    int mb = m0 + wm*64 + i*16 + ((lane>>4)<<2);
    for (int j=0;j<4;j++){
      int n = n0 + wn*64 + j*16 + lane15;
      float bb = bias[n];
      float sc = (n < scale_cols) ? 0.125f : 1.0f;
#pragma unroll
      for (int r=0;r<4;r++)
        C[(size_t)(mb+r)*Cstr + n] = f2bf((acc[i][j][r] + bb)*sc);
    }
  }
}

// ---------------- proj col-slice -> t[b][h][d][s] (s-contiguous) ----------------
__global__ __launch_bounds__(256) void vt_transpose(
    const unsigned short* __restrict__ proj, unsigned short* __restrict__ dst,
    int coloff){
  __shared__ unsigned short t[64*72];
  int bi = blockIdx.x;
  int sc = bi & 63, h = (bi>>6) & 15, b = bi >> 10;
  int s0 = sc*64;
  int tid = threadIdx.x;
  for (int it=0; it<2; ++it){
    int flat = it*256 + tid;          // 512 16B-chunks
    int r = flat >> 3, ch = flat & 7;
    *(int4*)&t[r*72 + ch*8] =
      *(const int4*)(proj + (size_t)(b*4096+s0+r)*5120 + coloff + h*64 + ch*8);
  }
  __syncthreads();
  for (int it=0; it<2; ++it){
    int flat = it*256 + tid;
    int d = flat & 63, ch = flat >> 6; // 0..7
    unsigned short tmp[8];
#pragma unroll
    for (int j=0;j<8;j++) tmp[j] = t[(ch*8+j)*72 + d];
    *(int4*)(dst + ((size_t)(b*16+h)*64 + d)*4096 + s0 + ch*8) = *(int4*)tmp;
  }
}

// ---------------- fused sliding-window + global-prefix attention ----------------
// Scores PRE-SKEWED: row r, col c -> sS col c + (c>=64 ? r : 0).
// Wave wv owns contiguous ct-range; B-pairs prefetched 5-deep; PV V 8-deep.
// XCD-swizzled blockIdx for window-row L2 locality.
#define SSTR 612
__global__ __launch_bounds__(256) void sliding_attn(
    const unsigned short* __restrict__ proj,   // [8192][5120]: q|k|v|kg|vg
    const unsigned short* __restrict__ vt,     // [2][16][64][4096]
    const float* __restrict__ amask,           // [2][4096]
    const unsigned char* __restrict__ maskb,   // is_index_masked (bytes; all 0)
    float* __restrict__ probs,                 // [2][4096][16][577]
    float* __restrict__ attn)                  // [2][4096][1024]
{
  __shared__ float sS[16*SSTR];                // 39168 B (scores f32 -> e bf16)
  __shared__ float srs[16];                    // per-row rs*mz for PV epilogue
  int bi = (blockIdx.x & 7)*1024 + (blockIdx.x >> 3);   // XCD-contiguous work id
  int ti = bi & 255, h = (bi>>8) & 15, b = bi >> 12;
  int t = ti*16;
  int chk = t >> 8;
  int qu = (chk < 15) ? chk*256 : 3584;
  int ql = (chk >= 1) ? chk*256 : 256;
  int tid = threadIdx.x, lane = tid & 63, wv = tid >> 6;
  int lane15 = lane & 15, kh = (lane >> 4) << 3;
  int rbase = (lane>>4)<<2;

  // A fragments: q rows t.. (global cols), k rows t.. (up), k rows t-1.. (low)
  s16x8 aq0, aq1, ak0a, ak0b, ak1a, ak1b;
  {
    int qrow = t + lane15;
    const unsigned short* qp = proj + (size_t)(b*4096+qrow)*5120 + h*64 + kh;
    aq0 = *(const s16x8*)qp;  aq1 = *(const s16x8*)(qp + 32);
    const unsigned short* kp0 = proj + (size_t)(b*4096+qrow)*5120 + 1024 + h*64 + kh;
    ak0a = *(const s16x8*)kp0; ak0b = *(const s16x8*)(kp0 + 32);
    int krow = t - 1 + lane15; if (krow < 0) krow = 0;
    const unsigned short* kp1 = proj + (size_t)(b*4096+krow)*5120 + 1024 + h*64 + kh;
    ak1a = *(const s16x8*)kp1; ak1b = *(const s16x8*)(kp1 + 32);
  }

  // QK: wave wv owns contiguous tiles; 2 batches of <=5 with deep prefetch
  {
    int ct0 = (wv==0)?0:(wv==1)?10:(wv==2)?19:28;
    int ntt = (wv==0)?10:9;
    s16x8 B0[5], B1[5];
#pragma unroll
    for (int bb=0; bb<2; ++bb){
      int base = ct0 + bb*5;
      int cnt = ct0 + ntt - base; if (cnt > 5) cnt = 5;
#pragma unroll
      for (int j=0;j<5;++j){
        if (j < cnt){
          int ct = base + j;
          int col = ct*16 + lane15;
          int brow, roff;
          if (ct < 4){        brow = col;               roff = 1024; }
          else if (ct < 20){  brow = ql + 1 + col - 64; roff = 0;
                              if (brow > 4095) brow = 4095; }
          else {              brow = qu + col - 320;    roff = 0; }
          const unsigned short* bp = proj + (size_t)(b*4096+brow)*5120 + roff + h*64 + kh;
          B0[j] = *(const s16x8*)bp;
          B1[j] = *(const s16x8*)(bp + 32);
        }
      }
#pragma unroll
      for (int j=0;j<5;++j){
        if (j < cnt){
          int ct = base + j;
          s16x8 A0 = (ct<4) ? aq0 : (ct<20) ? ak1a : ak0a;
          s16x8 A1 = (ct<4) ? aq1 : (ct<20) ? ak1b : ak0b;
          f32x4 acc = (f32x4){0.f,0.f,0.f,0.f};
          acc = __builtin_amdgcn_mfma_f32_16x16x32_bf16(A0, B0[j], acc, 0,0,0);
          acc = __builtin_amdgcn_mfma_f32_16x16x32_bf16(A1, B1[j], acc, 0,0,0);
          int col = ct*16 + lane15;
          if (col <= 576){
            int sk = (ct >= 4);
#pragma unroll
            for (int r=0;r<4;r++){
              int row = rbase + r;
              sS[row*SSTR + col + (sk ? row : 0)] = acc[r];
            }
          }
        }
      }
    }
  }
  __syncthreads();

  // softmax: wave wv owns rows wv*4..wv*4+3, all 4 interleaved
  {
    int r0 = wv*4;
    float low_add[4], up_add[4];
#pragma unroll
    for (int rr=0;rr<4;rr++){
      int s = t + r0 + rr;
      low_add[rr] = (s >= 1) ? amask[b*4096 + s - 1] : 0.f;
      up_add[rr]  = amask[b*4096 + s];
    }
    float ereg[4][10];
    float m4[4] = {-1e30f,-1e30f,-1e30f,-1e30f};
#pragma unroll
    for (int i=0;i<10;i++){
      int c = lane + i*64;
      bool inr = (c < 577);
      bool isup = (c >= 320), islow = (c >= 64) & !isup;
      int jup = c - 320, jlow = c - 64;
#pragma unroll
      for (int rr=0;rr<4;rr++){
        int r = r0 + rr;
        float v = -1e30f;
        if (inr){
          v = sS[r*SSTR + c + ((c>=64) ? r : 0)];
          int ii = (t + r) & 255;
          if (isup){
            bool valid = !((chk==15) & (jup >= 256 - ii));
            v = valid ? v + up_add[rr] : -1e30f;
          } else if (islow){
            bool valid = !((chk==0) & (jlow < 256 - ii));
            v = valid ? ((jlow==255) ? 0.f : v + low_add[rr]) : -1e30f;
          }
        }
        ereg[rr][i] = v;
        m4[rr] = fmaxf(m4[rr], v);
      }
    }
#pragma unroll
    for (int o=32;o;o>>=1){
#pragma unroll
      for (int rr=0;rr<4;rr++) m4[rr] = fmaxf(m4[rr], __shfl_xor(m4[rr], o));
    }
    float sum4[4] = {0.f,0.f,0.f,0.f};
#pragma unroll
    for (int i=0;i<10;i++){
      int c = lane + i*64;
      if (c < 577){
#pragma unroll
        for (int rr=0;rr<4;rr++){
          int r = r0 + rr;
          float e = __expf(ereg[rr][i] - m4[rr]);
          ereg[rr][i] = e;
          sum4[rr] += e;
          ((unsigned short*)&sS[r*SSTR])[c + ((c>=64) ? r : 0)] = f2bf(e);
        }
      }
    }
#pragma unroll
    for (int o=32;o;o>>=1){
#pragma unroll
      for (int rr=0;rr<4;rr++) sum4[rr] += __shfl_xor(sum4[rr], o);
    }
#pragma unroll
    for (int rr=0;rr<4;rr++){
      int r = r0 + rr, s = t + r;
      float rs = 1.f / sum4[rr];
      float mz = maskb[b*4096 + s] ? 0.f : 1.f;
      float pz = (s < 64) ? 0.f : mz;
      float* prow = probs + ((size_t)(b*4096+s)*16 + h)*577;
#pragma unroll
      for (int i=0;i<10;i++){
        int c = lane + i*64;
        if (c < 577) prow[c] = ereg[rr][i] * rs * pz;
      }
      // zero bf16 gaps: cols [64..63+r] and [577+r..607] (31 cols total)
      if (lane < 31){
        int zc = (lane < r) ? 64 + lane : 577 + lane;
        ((unsigned short*)&sS[r*SSTR])[zc] = 0;
      }
      if (lane == 0) srs[r] = rs * mz;
    }
  }
  __syncthreads();

  // PV: out[16][64]; wave wv owns d-subtile; K-dim = 608 (19 chunks of 32)
  // V-fragments prefetched 8-deep (fully unrolled, static indices)
  int dcol = wv*16 + lane15;
  const unsigned short* vtb = vt + ((size_t)(b*16+h)*64 + dcol)*4096;
  const unsigned short* prow16 = (const unsigned short*)(sS + (size_t)lane15*SSTR);
  s16x8 vb[8];
#pragma unroll
  for (int kc=0; kc<8; ++kc){
    int kk = kc*32 + kh;
    int key = (kk < 64) ? kk : (t - 320 + kk);
    key = key < 0 ? 0 : (key > 4088 ? 4088 : key);
    vb[kc] = *(const s16x8*)(vtb + key);
  }
  f32x4 oacc = (f32x4){0.f,0.f,0.f,0.f};
#pragma unroll
  for (int kc = 0; kc < 19; ++kc){
    s16x8 ap = *(const s16x8*)(prow16 + kc*32 + kh);
    oacc = __builtin_amdgcn_mfma_f32_16x16x32_bf16(ap, vb[kc & 7], oacc, 0,0,0);
    int kn = kc + 8;
    if (kn < 19){
      int kk = kn*32 + kh;
      int key = (kk < 64) ? kk : (t - 320 + kk);
      key = key < 0 ? 0 : (key > 4088 ? 4088 : key);
      vb[kn & 7] = *(const s16x8*)(vtb + key);
    }
  }
#pragma unroll
  for (int r=0;r<4;r++)
    attn[(size_t)(b*4096 + t + rbase + r)*1024 + h*64 + dcol] = oacc[r] * srs[rbase + r];
}

// ---------------- global attention: gs = qg·kg^T via MFMA ----------------
__global__ __launch_bounds__(256) void gs_a2(
    const unsigned short* __restrict__ qg,     // [128][1024]
    const unsigned short* __restrict__ proj,   // kg at col 3072
    const unsigned char* __restrict__ maskb,
    float* __restrict__ gp)                    // [2][16][64][4096] raw
{
  __shared__ unsigned short sQ[64*68];
  int bi = blockIdx.x;
  int sc = bi & 15, h = (bi>>4) & 15, b = bi >> 8;
  int tid = threadIdx.x, lane = tid & 63, wv = tid >> 6;
  int lane15 = lane & 15, kh = (lane >> 4) << 3;
  // stage qg head-slice [64 g][64 d]
#pragma unroll
  for (int it=0; it<2; ++it){
    int flat = it*256 + tid;          // 512 chunks of 8 shorts
    int g = flat >> 3, ch = (flat & 7) << 3;
    *(s16x8*)&sQ[g*68 + ch] = *(const s16x8*)(qg + (size_t)(b*64+g)*1024 + h*64 + ch);
  }
  __syncthreads();
  s16x8 a[4][2];
#pragma unroll
  for (int gt=0; gt<4; ++gt)
#pragma unroll
    for (int ks=0; ks<2; ++ks)
      a[gt][ks] = *(const s16x8*)&sQ[(gt*16+lane15)*68 + ks*32 + kh];
  int s0 = sc*256 + wv*64;
  float* gpb_ = gp + (size_t)(b*16+h)*64*4096;
#pragma unroll
  for (int st=0; st<4; ++st){
    int s = s0 + st*16 + lane15;
    const unsigned short* kp = proj + (size_t)(b*4096+s)*5120 + 3072 + h*64 + kh;
    s16x8 b0 = *(const s16x8*)kp;
    s16x8 b1 = *(const s16x8*)(kp + 32);
    bool msk = maskb[b*4096 + s] != 0;
    f32x4 acc[4];
#pragma unroll
    for (int gt=0; gt<4; ++gt){
      acc[gt] = (f32x4){0.f,0.f,0.f,0.f};
      acc[gt] = __builtin_amdgcn_mfma_f32_16x16x32_bf16(a[gt][0], b0, acc[gt], 0,0,0);
      acc[gt] = __builtin_amdgcn_mfma_f32_16x16x32_bf16(a[gt][1], b1, acc[gt], 0,0,0);
    }
#pragma unroll
    for (int gt=0; gt<4; ++gt){
#pragma unroll
      for (int r=0;r<4;r++){
        int g = gt*16 + (lane>>4)*4 + r;
        gpb_[(size_t)g*4096 + s] = msk ? -10000.f : acc[gt][r];
      }
    }
  }
}

// normalize gp rows in place (softmax over s), single pass, also emit bf16 copy
__global__ __launch_bounds__(256) void gs_norm(float* __restrict__ gp,
                                               unsigned short* __restrict__ gpb){
  __shared__ float red[8];
  int bi = blockIdx.x;                          // b*1024 + h*64 + g
  float* row = gp + (size_t)bi*4096;
  int tid = threadIdx.x, lane = tid & 63, wv = tid >> 6;
  float v[16];
  float m = -1e30f;
#pragma unroll
  for (int i=0;i<16;i++){
    v[i] = row[tid + i*256];
    m = fmaxf(m, v[i]);
  }
#pragma unroll
  for (int o=32;o;o>>=1) m = fmaxf(m, __shfl_xor(m, o));
  if (!lane) red[wv] = m;
  __syncthreads();
  m = fmaxf(fmaxf(red[0],red[1]), fmaxf(red[2],red[3]));
  float s = 0.f;
#pragma unroll
  for (int i=0;i<16;i++){
    float e = __expf(v[i] - m);
    v[i] = e;
    s += e;
  }
#pragma unroll
  for (int o=32;o;o>>=1) s += __shfl_xor(s, o);
  if (!lane) red[4+wv] = s;
  __syncthreads();
  s = red[4]+red[5]+red[6]+red[7];
  float rs = 1.f / s;
#pragma unroll
  for (int i=0;i<16;i++){
    float p = v[i] * rs;
    row[tid + i*256] = p;
    gpb[(size_t)bi*4096 + tid + i*256] = f2bf(p);
  }
}

// go partial GEMM: gop[bh][kc][64][64] = gp_bf[bh][g][kslice]·vgt[bh][d][kslice]^T
__global__ __launch_bounds__(256) void go_mfma(
    const unsigned short* __restrict__ gpb,    // [32][64][4096] bf16
    const unsigned short* __restrict__ vgt,    // [32][64][4096] bf16
    float* __restrict__ gop)                   // [32][8][64][64] f32
{
  int bi = blockIdx.x;
  int kc = bi & 7, bh = bi >> 3;
  int tid = threadIdx.x, lane = tid & 63, wv = tid >> 6;
  int lane15 = lane & 15, kh = (lane >> 4) << 3;
  const unsigned short* arow = gpb + ((size_t)bh*64 + wv*16 + lane15)*4096 + kh;
  const unsigned short* bbase = vgt + (size_t)bh*64*4096 + kh;
  f32x4 acc[4];
#pragma unroll
  for (int j=0;j<4;j++) acc[j] = (f32x4){0.f,0.f,0.f,0.f};
  for (int ks = 0; ks < 16; ++ks){
    int k = kc*512 + ks*32;
    s16x8 a = *(const s16x8*)(arow + k);
#pragma unroll
    for (int j=0;j<4;j++){
      s16x8 bv = *(const s16x8*)(bbase + (size_t)(j*16 + lane15)*4096 + k);
      acc[j] = __builtin_amdgcn_mfma_f32_16x16x32_bf16(a, bv, acc[j], 0,0,0);
    }
  }
  int rq = (lane >> 4) << 2;
  float* o = gop + ((size_t)bh*8 + kc)*4096;
#pragma unroll
  for (int j=0;j<4;j++)
#pragma unroll
    for (int r=0;r<4;r++)
      o[(wv*16 + rq + r)*64 + j*16 + lane15] = acc[j][r];
}

__global__ __launch_bounds__(256) void reduce_go2(
    const float* __restrict__ gop, float* __restrict__ attn){
  int flat = blockIdx.x*256 + threadIdx.x;    // < 131072
  int gd = flat & 4095, bh = flat >> 12;
  int b = bh >> 4, h = bh & 15;
  int g = gd >> 6, d = gd & 63;
  const float* p = gop + (size_t)bh*8*4096 + gd;
  float sum = 0.f;
#pragma unroll
  for (int c=0; c<8; ++c) sum += p[c*4096];
  attn[(size_t)(b*4096 + g)*1024 + h*64 + d] = sum;
}

// ---------------- launcher ----------------
extern "C" void kernel_launch(void* const* d_in, const int* in_sizes, int n_in,
                              void* d_out, int out_size, void* d_ws, size_t ws_size,
                              hipStream_t stream)
{
  const float* X     = (const float*)d_in[0];
  const float* amask = (const float*)d_in[1];
  const float* Wq  = (const float*)d_in[2];  const float* bq  = (const float*)d_in[3];
  const float* Wk  = (const float*)d_in[4];  const float* bk  = (const float*)d_in[5];
  const float* Wv  = (const float*)d_in[6];  const float* bv  = (const float*)d_in[7];
  const float* Wqg = (const float*)d_in[8];  const float* bqg = (const float*)d_in[9];
  const float* Wkg = (const float*)d_in[10]; const float* bkg = (const float*)d_in[11];
  const float* Wvg = (const float*)d_in[12]; const float* bvg = (const float*)d_in[13];
  const unsigned char* imask = (const unsigned char*)d_in[14];
  (void)in_sizes; (void)n_in; (void)out_size;

  // ws layout (bytes)
  const size_t XBF  = 0;               // 16,777,216 (Xbf; later gp_bf — exact fit)
  const size_t XG   = 16777216;        // 262,144
  const size_t WT   = 17039360;        // 10,485,760 (Wt cat; later gop 4 MB)
  const size_t WTQG = 27525120;        // 2,097,152
  const size_t BC   = 29622272;        // 20,480
  const size_t BQG  = 29642752;        // 4,096
  const size_t PROJ = 29646848;        // 83,886,080 ([8192][5120] bf16)
  const size_t QGO  = 113532928;       // 262,144
  const size_t VT   = 113795072;       // 16,777,216 (v^T; later vg^T — reuse)
  const size_t NEED = 130572288;
  if (ws_size < NEED) return;          // fail loudly (output stays poisoned)

  char* ws = (char*)d_ws;
  unsigned short* Xbf   = (unsigned short*)(ws + XBF);
  unsigned short* Xg    = (unsigned short*)(ws + XG);
  unsigned short* Wtcat = (unsigned short*)(ws + WT);
  unsigned short* Wtqg  = (unsigned short*)(ws + WTQG);
  float*          bc    = (float*)(ws + BC);
  float*          bqgo  = (float*)(ws + BQG);
  unsigned short* proj  = (unsigned short*)(ws + PROJ);
  unsigned short* qgo   = (unsigned short*)(ws + QGO);
  unsigned short* vt    = (unsigned short*)(ws + VT);
  unsigned short* gpb   = (unsigned short*)(ws + XBF);   // reuse Xbf (16.7 MB exact)
  float*          gop   = (float*)(ws + WT);             // reuse Wt region (4 MB)

  float* attn  = (float*)d_out;
  float* probs = (float*)d_out + 8388608;
  float* gp    = (float*)d_out + 84017152;

  cast_x<<<8192, 256, 0, stream>>>(X, Xbf);
  xg_gather<<<512, 256, 0, stream>>>(X, Xg);
  bias_cat_k<<<24, 256, 0, stream>>>(bq, bk, bv, bkg, bvg, bqg, bc, bqgo);
  WSrc srcs; srcs.p[0]=Wq; srcs.p[1]=Wk; srcs.p[2]=Wv; srcs.p[3]=Wqg; srcs.p[4]=Wkg; srcs.p[5]=Wvg;
  wt_transpose<<<1536, 256, 0, stream>>>(srcs, Wtcat, Wtqg);
  gemm_bt<<<dim3(40,64), 256, 0, stream>>>(Xbf, Wtcat, bc, proj, 1024, 1024, 5120, 1024);
  gemm_bt<<<dim3(8,1),  256, 0, stream>>>(Xg, Wtqg, bqgo, qgo, 1024, 1024, 1024, 1024);
  vt_transpose<<<2048, 256, 0, stream>>>(proj, vt, 2048);        // v^T
  sliding_attn<<<8192, 256, 0, stream>>>(proj, vt, amask, imask, probs, attn);
  vt_transpose<<<2048, 256, 0, stream>>>(proj, vt, 4096);        // vg^T (reuse buffer)
  gs_a2<<<512, 256, 0, stream>>>(qgo, proj, imask, gp);
  gs_norm<<<2048, 256, 0, stream>>>(gp, gpb);
  go_mfma<<<256, 256, 0, stream>>>(gpb, vt, gop);
  reduce_go2<<<512, 256, 0, stream>>>(gop, attn);
}